// Round 1
// 770.293 us; speedup vs baseline: 1.5509x; 1.5509x over previous
//
#include <hip/hip_runtime.h>
#include <cstdint>
#include <cstddef>

#define HH    128
#define VV    256
#define NB    8
#define NROW  2048        /* NB*VV  rows of h      */
#define NEROW 524288      /* NB*VV*VV rows of e    */
#define PROJ  (NROW*HH)   /* 262144 floats         */
#define EPSV  1e-5f

typedef __attribute__((ext_vector_type(8))) short short8v;  // 8 bf16 = 4 VGPR
typedef __attribute__((ext_vector_type(4))) float f32x4;

__device__ inline float4 f4add(float4 a, float4 b) {
    return make_float4(a.x+b.x, a.y+b.y, a.z+b.z, a.w+b.w);
}

// fp32 -> bf16 round-to-nearest-even (bit trick, NaN irrelevant here)
__device__ inline unsigned short f2bf(float x) {
    unsigned u = __float_as_uint(x);
    return (unsigned short)((u + 0x7fffu + ((u >> 16) & 1u)) >> 16);
}
__device__ inline float bf2f(unsigned short h) {
    return __uint_as_float(((unsigned)h) << 16);
}
// split 8 fp32 into hi/lo bf16 fragments (x ~= hi + lo, error ~2^-17 |x|)
__device__ inline void split8(float4 a, float4 b, short8v &hi, short8v &lo) {
    float v[8] = {a.x, a.y, a.z, a.w, b.x, b.y, b.z, b.w};
    #pragma unroll
    for (int i = 0; i < 8; ++i) {
        unsigned short h = f2bf(v[i]);
        hi[i] = (short)h;
        lo[i] = (short)f2bf(v[i] - bf2f(h));
    }
}

// ---------------------------------------------------------------------------
// K1: Uh/Vh/Ah/Bh = h @ W^T + b. grid (64,4): blockIdx.y picks the matrix,
// blockIdx.x the 32-row slab. 256 blocks total -> full CU coverage, and each
// block's weight working set is one 64KB matrix.
// ---------------------------------------------------------------------------
__global__ __launch_bounds__(256) void k1_proj(
    const float* __restrict__ h,
    const float* __restrict__ Uw, const float* __restrict__ Ub,
    const float* __restrict__ Vw, const float* __restrict__ Vb,
    const float* __restrict__ Aw, const float* __restrict__ Ab,
    const float* __restrict__ Bw, const float* __restrict__ Bb,
    float* __restrict__ ws)
{
    __shared__ float hs[32*136];
    const int t  = threadIdx.x;
    const int R0 = blockIdx.x * 32;
    const int m  = blockIdx.y;
    {
        const float4* src = (const float4*)(h + (size_t)R0*HH);
        #pragma unroll
        for (int ii = 0; ii < 4; ++ii) {
            int idx4 = t + 256*ii;            // 0..1023
            int r = idx4 >> 5, c = idx4 & 31;
            *(float4*)&hs[r*136 + c*4] = src[idx4];
        }
    }
    __syncthreads();
    const int o0 = (t & 15) * 8;
    const int jg = t >> 4;                    // 0..15, rows jg*2 .. jg*2+1
    const float* __restrict__ W  = (m==0)?Uw:(m==1)?Vw:(m==2)?Aw:Bw;
    const float* __restrict__ Bv = (m==0)?Ub:(m==1)?Vb:(m==2)?Ab:Bb;

    float acc[2][8];
    #pragma unroll
    for (int jj = 0; jj < 2; ++jj)
        #pragma unroll
        for (int d = 0; d < 8; ++d) acc[jj][d] = 0.f;
    for (int k4 = 0; k4 < 32; ++k4) {
        float4 w[8];
        #pragma unroll
        for (int d = 0; d < 8; ++d)
            w[d] = *(const float4*)(W + (size_t)(o0+d)*HH + k4*4);
        #pragma unroll
        for (int jj = 0; jj < 2; ++jj) {
            float4 ev = *(const float4*)&hs[(jg*2+jj)*136 + k4*4];
            #pragma unroll
            for (int d = 0; d < 8; ++d)
                acc[jj][d] += ev.x*w[d].x + ev.y*w[d].y
                            + ev.z*w[d].z + ev.w*w[d].w;
        }
    }
    float4 b0 = *(const float4*)(Bv + o0);
    float4 b1 = *(const float4*)(Bv + o0 + 4);
    float* outp = ws + (size_t)m * PROJ;
    #pragma unroll
    for (int jj = 0; jj < 2; ++jj) {
        int r = R0 + jg*2 + jj;
        float4 v0 = f4add(make_float4(acc[jj][0],acc[jj][1],acc[jj][2],acc[jj][3]), b0);
        float4 v1 = f4add(make_float4(acc[jj][4],acc[jj][5],acc[jj][6],acc[jj][7]), b1);
        *(float4*)(outp + (size_t)r*HH + o0)     = v0;
        *(float4*)(outp + (size_t)r*HH + o0 + 4) = v1;
    }
}

// ---------------------------------------------------------------------------
// K2 (MFMA version): per (b,i) block over all j.
//   Ce via split-bf16 MFMA (Eh*Wh + Eh*Wl + El*Wh, fp32 accum ~ fp32 exact)
//   e_new = Ce + Cb + Ah[b,j] + Bh[b,i]; store; BN partial sums;
//   agg[b,i] = sum_j (graph ? 0 : sigmoid(e_new) * Vh[b,j]).
// 4 waves; wave w owns o in [32w,32w+32) for ALL 256 j (agg stays wave-local).
// Cw hi/lo fragments in registers (loaded once). e staged fp32 in LDS,
// 64-row phases, double-buffered, register prefetch of next phase issued
// before compute so HBM latency hides under MFMA + epilogue.
// ---------------------------------------------------------------------------
__global__ __launch_bounds__(256, 2) void k2_main(
    const float* __restrict__ e,
    const int*   __restrict__ graph,
    const float* __restrict__ Cw, const float* __restrict__ Cb,
    const float* __restrict__ ws,
    float* __restrict__ agg_out,
    float* __restrict__ esum, float* __restrict__ esumsq,
    float* __restrict__ e_new_out)
{
    __shared__ float lds[2][64 * 132];        // 2 x 33.8 KB (pad 132: 2-way max)
    const int t  = threadIdx.x;
    const int l  = t & 63;
    const int wv = t >> 6;                    // wave 0..3
    const int bi = blockIdx.x;                // b*V + i
    const int b  = bi >> 8;
    const int ob = wv * 32;                   // wave's o-base
    const int lr = l & 15;                    // A-row / B-col / C-col in frag
    const int lg = l >> 4;                    // 0..3 -> k-offset & C-row group

    const float* __restrict__ Vh = ws + (size_t)PROJ;
    const float* __restrict__ Ah = ws + 2*(size_t)PROJ;
    const float* __restrict__ Bh = ws + 3*(size_t)PROJ;

    const int o0 = ob + lr, o1 = o0 + 16;
    const float bh0 = Bh[(size_t)bi*HH + o0];
    const float bh1 = Bh[(size_t)bi*HH + o1];
    const float cb0 = Cb[o0], cb1 = Cb[o1];

    // B-operand fragments: lane holds Cw[o][k..k+8) = W^T column o. hi/lo split.
    short8v Whi[2][4], Wlo[2][4];
    #pragma unroll
    for (int n = 0; n < 2; ++n)
        #pragma unroll
        for (int kk = 0; kk < 4; ++kk) {
            const float* wp = Cw + (size_t)(ob + n*16 + lr)*HH + kk*32 + lg*8;
            split8(*(const float4*)wp, *(const float4*)(wp + 4),
                   Whi[n][kk], Wlo[n][kk]);
        }

    // prologue: stage phase 0
    const float4* esrc = (const float4*)(e + (size_t)bi * VV * HH);
    float4 pf[8];
    #pragma unroll
    for (int ii = 0; ii < 8; ++ii) pf[ii] = esrc[t + 256*ii];
    #pragma unroll
    for (int ii = 0; ii < 8; ++ii) {
        int idx4 = t + 256*ii, r = idx4 >> 5, c = idx4 & 31;
        *(float4*)&lds[0][r*132 + c*4] = pf[ii];
    }
    __syncthreads();

    float se0 = 0.f, se1 = 0.f, sq0 = 0.f, sq1 = 0.f, agg0 = 0.f, agg1 = 0.f;

    #pragma unroll 1
    for (int p = 0; p < 4; ++p) {
        // issue next-phase global loads early (hide under MFMA + epilogue)
        if (p < 3) {
            const float4* s2 = esrc + (size_t)(p + 1) * 64 * 32;
            #pragma unroll
            for (int ii = 0; ii < 8; ++ii) pf[ii] = s2[t + 256*ii];
        }

        const float* buf = lds[p & 1];
        f32x4 acc[4][2] = {};                 // [m][n], zero-init

        #pragma unroll
        for (int kk = 0; kk < 4; ++kk) {
            short8v Ahi[4], Alo[4];
            #pragma unroll
            for (int m = 0; m < 4; ++m) {
                const float* ap = buf + (m*16 + lr)*132 + kk*32 + lg*8;
                split8(*(const float4*)ap, *(const float4*)(ap + 4),
                       Ahi[m], Alo[m]);
            }
            #pragma unroll
            for (int m = 0; m < 4; ++m)
                #pragma unroll
                for (int n = 0; n < 2; ++n) {
                    acc[m][n] = __builtin_amdgcn_mfma_f32_16x16x32_bf16(
                                    Ahi[m], Whi[n][kk], acc[m][n], 0, 0, 0);
                    acc[m][n] = __builtin_amdgcn_mfma_f32_16x16x32_bf16(
                                    Ahi[m], Wlo[n][kk], acc[m][n], 0, 0, 0);
                    acc[m][n] = __builtin_amdgcn_mfma_f32_16x16x32_bf16(
                                    Alo[m], Whi[n][kk], acc[m][n], 0, 0, 0);
                }
        }

        // epilogue for this phase's 64 rows
        #pragma unroll
        for (int m = 0; m < 4; ++m)
            #pragma unroll
            for (int r = 0; r < 4; ++r) {
                const int j = p*64 + m*16 + lg*4 + r;   // C-row mapping (m89)
                const float* AhR = Ah + (size_t)(b*VV + j)*HH;
                const float* VhR = Vh + (size_t)(b*VV + j)*HH;
                const float gm = graph[(size_t)bi*VV + j] ? 0.f : 1.f;
                float* eo = e_new_out + ((size_t)bi*VV + j)*HH;
                float v0 = acc[m][0][r] + cb0 + bh0 + AhR[o0];
                float v1 = acc[m][1][r] + cb1 + bh1 + AhR[o1];
                eo[o0] = v0; eo[o1] = v1;
                se0 += v0; sq0 += v0*v0;
                se1 += v1; sq1 += v1*v1;
                agg0 += gm * VhR[o0] / (1.f + __expf(-v0));
                agg1 += gm * VhR[o1] / (1.f + __expf(-v1));
            }

        // write next phase into the other buffer, one sync per phase
        if (p < 3) {
            float* dst = lds[(p + 1) & 1];
            #pragma unroll
            for (int ii = 0; ii < 8; ++ii) {
                int idx4 = t + 256*ii, r = idx4 >> 5, c = idx4 & 31;
                *(float4*)&dst[r*132 + c*4] = pf[ii];
            }
            __syncthreads();
        }
    }

    // reduce across the 4 row-groups (lanes l, l^16, l^32 share the same o)
    se0 += __shfl_xor(se0, 16); se0 += __shfl_xor(se0, 32);
    sq0 += __shfl_xor(sq0, 16); sq0 += __shfl_xor(sq0, 32);
    se1 += __shfl_xor(se1, 16); se1 += __shfl_xor(se1, 32);
    sq1 += __shfl_xor(sq1, 16); sq1 += __shfl_xor(sq1, 32);
    agg0 += __shfl_xor(agg0, 16); agg0 += __shfl_xor(agg0, 32);
    agg1 += __shfl_xor(agg1, 16); agg1 += __shfl_xor(agg1, 32);
    if (l < 16) {
        const int oA = ob + l, oB = oA + 16;
        atomicAdd(&esum[oA],   se0);  atomicAdd(&esumsq[oA], sq0);
        atomicAdd(&esum[oB],   se1);  atomicAdd(&esumsq[oB], sq1);
        agg_out[(size_t)bi*HH + oA] = agg0;
        agg_out[(size_t)bi*HH + oB] = agg1;
    }
}

// ---------------------------------------------------------------------------
// K3a: h_new = Uh + agg, plus per-channel sum/sumsq. grid 128, block 256.
// ---------------------------------------------------------------------------
__global__ __launch_bounds__(256) void k3a_hnew(
    const float* __restrict__ Uh, const float* __restrict__ agg,
    float* __restrict__ hnew, float* __restrict__ hsum, float* __restrict__ hsumsq)
{
    __shared__ float red[512];
    const int t = threadIdx.x;
    const int o = t & 127;
    const int g = t >> 7;
    const int R0 = blockIdx.x * 16;
    float s = 0.f, s2 = 0.f;
    #pragma unroll
    for (int rr = 0; rr < 8; ++rr) {
        size_t idx = (size_t)(R0 + g*8 + rr)*HH + o;
        float v = Uh[idx] + agg[idx];
        hnew[idx] = v;
        s += v; s2 += v*v;
    }
    red[t] = s; red[256 + t] = s2;
    __syncthreads();
    if (t < 128) {
        atomicAdd(&hsum[o],   red[t]     + red[t + 128]);
        atomicAdd(&hsumsq[o], red[256+t] + red[256 + t + 128]);
    }
}

// ---------------------------------------------------------------------------
// K3b: fold batchnorm into per-channel affine (a,c) for h and e. 1x128.
// stats layout: [esum|esumsq|hsum|hsumsq] each 128 floats; coef [a_h|c_h|a_e|c_e]
// ---------------------------------------------------------------------------
__global__ void k3b_coef(const float* __restrict__ st, float* __restrict__ coef,
    const float* __restrict__ gh, const float* __restrict__ bh,
    const float* __restrict__ ge, const float* __restrict__ be)
{
    int o = threadIdx.x;
    float es = st[o], eq = st[128+o], hs = st[256+o], hq = st[384+o];
    float me = es * (1.f/(float)NEROW);
    float ve = eq * (1.f/(float)NEROW) - me*me;
    float ae = ge[o] * rsqrtf(ve + EPSV);
    float ce = be[o] - me*ae;
    float mh = hs * (1.f/(float)NROW);
    float vh = hq * (1.f/(float)NROW) - mh*mh;
    float ah = gh[o] * rsqrtf(vh + EPSV);
    float ch = bh[o] - mh*ah;
    coef[o] = ah; coef[128+o] = ch; coef[256+o] = ae; coef[384+o] = ce;
}

// ---------------------------------------------------------------------------
// K3c: h_out = h_in + relu(a*h_new + c). grid 256, block 256, 1 float4 each.
// ---------------------------------------------------------------------------
__global__ __launch_bounds__(256) void k3c_hout(
    const float* __restrict__ h_in, const float* __restrict__ hnew,
    const float* __restrict__ coef, float* __restrict__ out_h)
{
    int idx = blockIdx.x*256 + threadIdx.x;       // < 65536
    int o4 = (idx & 31) * 4;
    float4 a = *(const float4*)(coef + o4);
    float4 c = *(const float4*)(coef + 128 + o4);
    float4 v = ((const float4*)hnew)[idx];
    float4 x = ((const float4*)h_in)[idx];
    float4 r;
    r.x = x.x + fmaxf(fmaf(a.x, v.x, c.x), 0.f);
    r.y = x.y + fmaxf(fmaf(a.y, v.y, c.y), 0.f);
    r.z = x.z + fmaxf(fmaf(a.z, v.z, c.z), 0.f);
    r.w = x.w + fmaxf(fmaf(a.w, v.w, c.w), 0.f);
    ((float4*)out_h)[idx] = r;
}

// ---------------------------------------------------------------------------
// K4: e_out = e_in + relu(a_e*e_new + c_e), in-place over e_new region.
// grid-stride float4; stride % 32 == 0 keeps channel group invariant.
// ---------------------------------------------------------------------------
__global__ __launch_bounds__(256) void k4_eout(
    const float* __restrict__ e_in, const float* __restrict__ coef,
    float* __restrict__ e_io)
{
    const size_t total4 = (size_t)NEROW * HH / 4;     // 16777216
    size_t idx = (size_t)blockIdx.x * 256 + threadIdx.x;
    const size_t stride = (size_t)gridDim.x * 256;    // 2M, % 32 == 0
    const int o4 = ((int)(idx & 31)) * 4;
    const float4 a = *(const float4*)(coef + 256 + o4);
    const float4 c = *(const float4*)(coef + 384 + o4);
    const float4* ein4 = (const float4*)e_in;
    float4* eio4 = (float4*)e_io;
    for (; idx < total4; idx += stride) {
        float4 v = eio4[idx];
        float4 x = ein4[idx];
        float4 r;
        r.x = x.x + fmaxf(fmaf(a.x, v.x, c.x), 0.f);
        r.y = x.y + fmaxf(fmaf(a.y, v.y, c.y), 0.f);
        r.z = x.z + fmaxf(fmaf(a.z, v.z, c.z), 0.f);
        r.w = x.w + fmaxf(fmaf(a.w, v.w, c.w), 0.f);
        eio4[idx] = r;
    }
}

// ---------------------------------------------------------------------------
extern "C" void kernel_launch(void* const* d_in, const int* in_sizes, int n_in,
                              void* d_out, int out_size, void* d_ws, size_t ws_size,
                              hipStream_t stream)
{
    (void)in_sizes; (void)n_in; (void)out_size; (void)ws_size;
    const float* h     = (const float*)d_in[0];
    const float* e     = (const float*)d_in[1];
    const int*   graph = (const int*)  d_in[2];
    const float* Uw = (const float*)d_in[3];
    const float* Ub = (const float*)d_in[4];
    const float* Vw = (const float*)d_in[5];
    const float* Vb = (const float*)d_in[6];
    const float* Aw = (const float*)d_in[7];
    const float* Ab = (const float*)d_in[8];
    const float* Bw = (const float*)d_in[9];
    const float* Bb = (const float*)d_in[10];
    const float* Cw = (const float*)d_in[11];
    const float* Cb = (const float*)d_in[12];
    const float* gamma_h = (const float*)d_in[13];
    const float* beta_h  = (const float*)d_in[14];
    const float* gamma_e = (const float*)d_in[15];
    const float* beta_e  = (const float*)d_in[16];

    float* out_h = (float*)d_out;
    float* out_e = out_h + (size_t)NROW * HH;     // e_new scratch, then e_out

    float* ws    = (float*)d_ws;
    float* Uh    = ws;                            // [0,PROJ) U; then V,A,B
    float* aggp  = ws + 4*(size_t)PROJ;
    float* hnew  = ws + 5*(size_t)PROJ;
    float* stats = ws + 6*(size_t)PROJ;           // 512 floats sums + 512 coef
    float* coef  = stats + 512;

    hipMemsetAsync(stats, 0, 512*sizeof(float), stream);
    k1_proj<<<dim3(64, 4), 256, 0, stream>>>(h, Uw,Ub, Vw,Vb, Aw,Ab, Bw,Bb, ws);
    k2_main<<<2048, 256, 0, stream>>>(e, graph, Cw, Cb, ws, aggp,
                                      stats, stats+128, out_e);
    k3a_hnew<<<128, 256, 0, stream>>>(Uh, aggp, hnew, stats+256, stats+384);
    k3b_coef<<<1, 128, 0, stream>>>(stats, coef, gamma_h, beta_h, gamma_e, beta_e);
    k3c_hout<<<256, 256, 0, stream>>>(h, hnew, coef, out_h);
    k4_eout<<<8192, 256, 0, stream>>>(e, coef, out_e);
}